// Round 7
// baseline (263.544 us; speedup 1.0000x reference)
//
#include <hip/hip_runtime.h>
#include <hip/hip_bf16.h>

#define D_MODEL 1024
#define NHEADS 16
#define DKH 64
#define BATCH 4
#define SEQ 2048
#define BH_ (BATCH*NHEADS)
#define MROWS (BATCH*SEQ)

typedef __attribute__((ext_vector_type(8))) short bf16x8;
typedef __attribute__((ext_vector_type(4))) float f32x4;
typedef __attribute__((ext_vector_type(4))) short short4v;

static __device__ __forceinline__ unsigned short f2b(float f){
  union { float f; unsigned u; } v; v.f = f;
  unsigned u = v.u;
  return (unsigned short)((u + 0x7FFFu + ((u >> 16) & 1u)) >> 16);
}
static __device__ __forceinline__ float b2f(unsigned short h){
  union { unsigned u; float f; } v; v.u = ((unsigned)h) << 16; return v.f;
}

static __device__ __forceinline__ f32x4 mfma16(bf16x8 a, bf16x8 b, f32x4 c){
  return __builtin_amdgcn_mfma_f32_16x16x32_bf16(a, b, c, 0, 0, 0);
}

static __device__ __forceinline__ float fexp2(float x){
#if __has_builtin(__builtin_amdgcn_exp2f)
  return __builtin_amdgcn_exp2f(x);
#else
  float r; asm("v_exp_f32 %0, %1" : "=v"(r) : "v"(x)); return r;
#endif
}
static __device__ __forceinline__ float max3f(float a, float b, float c){
  return fmaxf(fmaxf(a, b), c);     // fuses to v_max3_f32
}

static __device__ __forceinline__ void gload_lds16(const unsigned short* g, void* l){
  __builtin_amdgcn_global_load_lds((const __attribute__((address_space(1))) void*)g,
                                   (__attribute__((address_space(3))) void*)l,
                                   16, 0, 0);
}

// Softmax-scale folded into Q at projection time: 1/sqrt(64) * log2(e)
#define QSCALE 0.1803368801111137f

// ---------------- merged prep: x->bf16 | weights->bf16 | rope table ----------------
// grid = 8192 (x) + 4096 (weights) + 256 (tab) = 12544 blocks of 256
__global__ void prep_kernel(const float* __restrict__ x,
                            const float* __restrict__ wq, const float* __restrict__ wk,
                            const float* __restrict__ wv, const float* __restrict__ wo,
                            const int* __restrict__ pos,
                            unsigned short* __restrict__ xb,
                            unsigned short* __restrict__ wcat,
                            unsigned short* __restrict__ wob,
                            float2* __restrict__ tab){
  const int bid = blockIdx.x;
  if (bid < 8192){
    int i = bid*256 + threadIdx.x;               // [0, 2097152) float4s of x
    float4 f = ((const float4*)x)[i];
    short4v o;
    o.x = (short)f2b(f.x); o.y = (short)f2b(f.y);
    o.z = (short)f2b(f.z); o.w = (short)f2b(f.w);
    ((short4v*)xb)[i] = o;
  } else if (bid < 8192 + 4096){
    int i = (bid - 8192)*256 + threadIdx.x;      // [0, 1048576) float4s of weights
    int seg = i >> 18;
    int j = i & 0x3FFFF;
    const float* s = (seg==0) ? wq : (seg==1) ? wk : (seg==2) ? wv : wo;
    unsigned short* d = (seg < 3) ? (wcat + ((size_t)seg << 20)) : wob;
    float4 f = ((const float4*)s)[j];
    short4v o;
    o.x = (short)f2b(f.x); o.y = (short)f2b(f.y);
    o.z = (short)f2b(f.z); o.w = (short)f2b(f.w);
    ((short4v*)d)[j] = o;
  } else {
    int i = (bid - 12288)*256 + threadIdx.x;     // [0, 65536) table entries
    int s = i >> 5, j = i & 31;
    float p = (float)pos[s];
    float fr = expf(-((float)(2*j) * (1.0f/DKH)) * 9.210340371976184f); // theta^(-2j/dk)
    float sn, cs;
    sincosf(p * fr, &sn, &cs);
    tab[i] = make_float2(cs, sn);
  }
}

// ---------------- NT GEMM, m97-style: global_load_lds staging ----------------
// C = A(MxK) * Bw(NxK)^T
// MODE 0: N=3072 fused QKV. which = n0>>10 (uniform per block):
//   which==0 : RoPE + scale by QSCALE, scatter bf16 into Q[(b,h,s,d)]
//   which==1 : RoPE, scatter bf16 into K[(b,h,s,d)]
//   which==2 : transpose 128x128 tile through LDS, write V^T[(b,h,d,s)]
// MODE 1: fp32 row-major MxN (output projection)
#define BM 128
#define BN 128
#define BKG 64

template<int MODE>
__global__ __launch_bounds__(256, 3) void gemm_nt(const unsigned short* __restrict__ A,
                                                  const unsigned short* __restrict__ Bw,
                                                  void* __restrict__ C,
                                                  const float2* __restrict__ tab,
                                                  int M, int N, int K)
{
  __shared__ unsigned short smem[BM*BKG + BN*BKG];   // As | Bs ; reused for V transpose
  unsigned short* As = smem;
  unsigned short* Bs = smem + BM*BKG;
  const int t = threadIdx.x;
  const int lane = t & 63;
  const int wv = t >> 6;
  const int wr = wv >> 1, wc = wv & 1;
  const int l15 = lane & 15, l4 = lane >> 4;
  const int m0 = blockIdx.y*BM, n0 = blockIdx.x*BN;

  f32x4 acc[4][4] = {};

  const int srow = lane >> 3;          // 0..7 within 8-row chunk
  const int sce  = (lane & 7) * 8;     // element offset in k within row

  for (int kt = 0; kt < K; kt += BKG){
    __syncthreads();
    #pragma unroll
    for (int jj = 0; jj < 4; ++jj){
      const int i = wv + jj*4;
      const int row = i*8 + srow;
      gload_lds16(A  + (size_t)(m0 + row)*K + kt + sce, (char*)As + i*1024 + lane*16);
      gload_lds16(Bw + (size_t)(n0 + row)*K + kt + sce, (char*)Bs + i*1024 + lane*16);
    }
    __syncthreads();
    #pragma unroll
    for (int kk = 0; kk < 2; ++kk){
      bf16x8 af[4], bfr[4];
      #pragma unroll
      for (int mi = 0; mi < 4; ++mi)
        af[mi] = *(const bf16x8*)((const char*)As + (wr*64 + mi*16 + l15)*128 + kk*64 + l4*16);
      #pragma unroll
      for (int ni = 0; ni < 4; ++ni)
        bfr[ni] = *(const bf16x8*)((const char*)Bs + (wc*64 + ni*16 + l15)*128 + kk*64 + l4*16);
      #pragma unroll
      for (int mi = 0; mi < 4; ++mi)
        #pragma unroll
        for (int ni = 0; ni < 4; ++ni)
          acc[mi][ni] = mfma16(af[mi], bfr[ni], acc[mi][ni]);
    }
  }

  if (MODE == 1){
    #pragma unroll
    for (int mi = 0; mi < 4; ++mi)
      #pragma unroll
      for (int ni = 0; ni < 4; ++ni)
        #pragma unroll
        for (int r = 0; r < 4; ++r){
          int row = m0 + wr*64 + mi*16 + l4*4 + r;
          int col = n0 + wc*64 + ni*16 + l15;
          ((float*)C)[(size_t)row*N + col] = acc[mi][ni][r];
        }
    return;
  }

  const int which = n0 >> 10;            // 0=Q 1=K 2=V (uniform per block)

  if (which == 2){
    // ---- V path: transpose 128x128 tile via LDS, write (bh, d, s) ----
    __syncthreads();   // done reading As/Bs
    #pragma unroll
    for (int mi = 0; mi < 4; ++mi)
      #pragma unroll
      for (int ni = 0; ni < 4; ++ni){
        int d_l = wc*64 + ni*16 + l15;            // 0..127 (2 heads)
        int s0  = wr*64 + mi*16 + l4*4;           // 0..124 step 4
        short4v pk;
        pk.x = (short)f2b(acc[mi][ni][0]);
        pk.y = (short)f2b(acc[mi][ni][1]);
        pk.z = (short)f2b(acc[mi][ni][2]);
        pk.w = (short)f2b(acc[mi][ni][3]);
        int byte = d_l*256 + ((s0*2) ^ ((d_l & 7) << 4));
        *(short4v*)((char*)smem + byte) = pk;
      }
    __syncthreads();
    const int d_l = t >> 1;                        // 0..127
    const int half = t & 1;                        // s half (64 each)
    const int hb = (n0 & 1023) >> 6;               // base head of this block pair
    const int b = m0 >> 11;
    const int s_b = m0 & (SEQ-1);                  // s offset WITHIN the batch
    const int bh = b*NHEADS + hb + (d_l >> 6);
    const int d = d_l & 63;
    unsigned short* vt = (unsigned short*)C + 2*((size_t)BH_*SEQ*DKH);
    unsigned short* dst = vt + ((size_t)bh*DKH + d)*SEQ + s_b + half*64;
    #pragma unroll
    for (int c = 0; c < 8; ++c){                   // 8 x 8 bf16 = full 64-s half
      int sl = half*64 + c*8;
      int byte = d_l*256 + ((sl*2) ^ ((d_l & 7) << 4));
      *(bf16x8*)(dst + c*8) = *(const bf16x8*)((const char*)smem + byte);
    }
    return;
  }

  // ---- Q/K path: RoPE via table (+QSCALE for Q), scatter to (b,h,s,d) ----
  unsigned short* qk = (unsigned short*)C + (size_t)which*((size_t)BH_*SEQ*DKH);
  const float oscale = (which == 0) ? QSCALE : 1.0f;
  #pragma unroll
  for (int ni = 0; ni < 4; ++ni){
    int col = n0 + wc*64 + ni*16 + l15;
    int cl = col & 1023;
    int h = cl >> 6, dd = cl & (DKH-1);
    int j = dd >> 1;
    bool odd = dd & 1;
    #pragma unroll
    for (int mi = 0; mi < 4; ++mi)
      #pragma unroll
      for (int r = 0; r < 4; ++r){
        int row = m0 + wr*64 + mi*16 + l4*4 + r;
        int b = row >> 11, s = row & (SEQ-1);
        float2 cst = tab[s*32 + j];
        float xv = acc[mi][ni][r];
        float pv = __shfl_xor(xv, 1);
        float res = odd ? fmaf(xv, cst.x,  pv*cst.y)
                        : fmaf(xv, cst.x, -pv*cst.y);
        qk[((size_t)(b*NHEADS + h)*SEQ + s)*DKH + dd] = f2b(res * oscale);
      }
  }
}

// ---------------- causal flash attention, 4 waves x 32 q-rows ----------------
#define QW 32
#define QB 128
#define KVB 64

__global__ __launch_bounds__(256, 3) void attn_kernel(const unsigned short* __restrict__ Q,
                                                      const unsigned short* __restrict__ Kw,
                                                      const unsigned short* __restrict__ Vt,
                                                      unsigned short* __restrict__ Ob)
{
  __shared__ unsigned short Ks[2][KVB*64];
  __shared__ unsigned short Vs[2][KVB*64];
  __shared__ unsigned short Ps[4][QW*KVB];

  const int t = threadIdx.x;
  const int lane = t & 63;
  const int wv = t >> 6;
  const int l15 = lane & 15, l4 = lane >> 4;

  const int bid = blockIdx.x;
  const int bh = bid & (BH_-1);
  const int qt = (SEQ/QB - 1) - (bid >> 6);
  const int q0 = qt * QB;
  const int qw0 = q0 + wv*QW;

  const unsigned short* kg = Kw + (size_t)bh*SEQ*DKH;
  const unsigned short* vg = Vt + (size_t)bh*DKH*SEQ;
  const unsigned short* qg = Q  + ((size_t)bh*SEQ + qw0)*DKH;

  bf16x8 qa[2][2];
  #pragma unroll
  for (int qi = 0; qi < 2; ++qi)
    #pragma unroll
    for (int c = 0; c < 2; ++c)
      qa[qi][c] = *(const bf16x8*)(qg + (qi*16 + l15)*DKH + c*32 + l4*8);

  // scores arrive pre-scaled into log2 domain (QSCALE folded into Q)
  float m_r[2] = {-1e30f, -1e30f};
  float l_r[2] = {0.f, 0.f};
  f32x4 oacc[2][4] = {};

  const int srow = t >> 3;
  const int scb  = (t & 7) * 16;
  const int sko  = scb ^ ((srow & 7) << 4);
  const size_t vstride = (size_t)SEQ * 2;

  const int ntB   = q0/KVB + 2;
  const int twmax = (qw0 + QW - 1) >> 6;

  bf16x8 kl0, kl1, vl0, vl1;
  {
    const char* ksrc = (const char*)kg;
    const char* vsrc = (const char*)vg;
    kl0 = *(const bf16x8*)(ksrc + srow*128 + sko);
    kl1 = *(const bf16x8*)(ksrc + (srow+32)*128 + sko);
    vl0 = *(const bf16x8*)(vsrc + (size_t)srow*vstride + sko);
    vl1 = *(const bf16x8*)(vsrc + (size_t)(srow+32)*vstride + sko);
    *(bf16x8*)((char*)Ks[0] + srow*128 + scb)      = kl0;
    *(bf16x8*)((char*)Ks[0] + (srow+32)*128 + scb) = kl1;
    *(bf16x8*)((char*)Vs[0] + srow*128 + scb)      = vl0;
    *(bf16x8*)((char*)Vs[0] + (srow+32)*128 + scb) = vl1;
  }

  for (int tt = 0; tt < ntB; ++tt){
    const int cur = tt & 1;
    __syncthreads();
    const bool pre = (tt + 1 < ntB);
    if (pre){
      const size_t kvoff = (size_t)(tt+1) * KVB;
      const char* ksrc = (const char*)kg + kvoff*128;
      const char* vsrc = (const char*)vg + kvoff*2;
      kl0 = *(const bf16x8*)(ksrc + srow*128 + sko);
      kl1 = *(const bf16x8*)(ksrc + (srow+32)*128 + sko);
      vl0 = *(const bf16x8*)(vsrc + (size_t)srow*vstride + sko);
      vl1 = *(const bf16x8*)(vsrc + (size_t)(srow+32)*vstride + sko);
    }

    if (tt <= twmax){
      const char* kb = (const char*)Ks[cur];
      const char* vb = (const char*)Vs[cur];
      char* pb = (char*)Ps[wv];
      const int sw = (l15 & 7) << 4;
      const bool needmask = (tt == twmax);

      f32x4 sacc[4][2];
      __builtin_amdgcn_s_setprio(1);
      #pragma unroll
      for (int kt = 0; kt < 4; ++kt){
        const int krow = kt*16 + l15;
        bf16x8 kf0 = *(const bf16x8*)(kb + krow*128 + ((l4*16) ^ sw));
        bf16x8 kf1 = *(const bf16x8*)(kb + krow*128 + ((64 + l4*16) ^ sw));
        #pragma unroll
        for (int qi = 0; qi < 2; ++qi){
          f32x4 a = {};
          a = mfma16(kf0, qa[qi][0], a);
          a = mfma16(kf1, qa[qi][1], a);
          sacc[kt][qi] = a;
        }
      }
      __builtin_amdgcn_s_setprio(0);

      const int kv0 = tt * KVB;
      #pragma unroll
      for (int qi = 0; qi < 2; ++qi){
        const int qrow = qw0 + qi*16 + l15;
        float p[16];
        #pragma unroll
        for (int kt = 0; kt < 4; ++kt)
          #pragma unroll
          for (int r = 0; r < 4; ++r){
            float xx = sacc[kt][qi][r];
            if (needmask){
              int kvg = kv0 + kt*16 + l4*4 + r;
              xx = (kvg > qrow) ? -1e30f : xx;
            }
            p[kt*4+r] = xx;
          }
        float t0 = max3f(p[0], p[1], p[2]);
        float t1 = max3f(p[3], p[4], p[5]);
        float t2 = max3f(p[6], p[7], p[8]);
        float t3 = max3f(p[9], p[10], p[11]);
        float t4 = max3f(p[12], p[13], p[14]);
        float mloc = fmaxf(max3f(t0, t1, t2), max3f(t3, t4, p[15]));
        mloc = fmaxf(mloc, __shfl_xor(mloc, 16));
        mloc = fmaxf(mloc, __shfl_xor(mloc, 32));

        const bool skip = __all(mloc - m_r[qi] <= 12.0f);   // defer-max (T13)
        float mn = m_r[qi];
        if (!skip){
          mn = fmaxf(m_r[qi], mloc);
          float alpha = fexp2(m_r[qi] - mn);
          m_r[qi] = mn;
          l_r[qi] *= alpha;
          float ar[4];
          #pragma unroll
          for (int r = 0; r < 4; ++r) ar[r] = __shfl(alpha, l4*4 + r);
          #pragma unroll
          for (int dt = 0; dt < 4; ++dt)
            #pragma unroll
            for (int r = 0; r < 4; ++r) oacc[qi][dt][r] *= ar[r];
        }
        float rs = 0.f;
        #pragma unroll
        for (int i = 0; i < 16; ++i){ p[i] = fexp2(p[i] - mn); rs += p[i]; }
        rs += __shfl_xor(rs, 16);
        rs += __shfl_xor(rs, 32);
        l_r[qi] += rs;

        char* pr = pb + (qi*16 + l15)*128;
        #pragma unroll
        for (int kt = 0; kt < 4; ++kt){
          unsigned u0, u1;
          asm("v_cvt_pk_bf16_f32 %0, %1, %2" : "=v"(u0) : "v"(p[kt*4+0]), "v"(p[kt*4+1]));
          asm("v_cvt_pk_bf16_f32 %0, %1, %2" : "=v"(u1) : "v"(p[kt*4+2]), "v"(p[kt*4+3]));
          unsigned long long uu = (unsigned long long)u0 | ((unsigned long long)u1 << 32);
          *(unsigned long long*)(pr + ((kt*32 + l4*8) ^ sw)) = uu;
        }
      }

      bf16x8 pa[2][2];
      #pragma unroll
      for (int qi = 0; qi < 2; ++qi){
        const char* pr = pb + (qi*16 + l15)*128;
        pa[qi][0] = *(const bf16x8*)(pr + ((l4*16) ^ sw));
        pa[qi][1] = *(const bf16x8*)(pr + ((64 + l4*16) ^ sw));
      }

      __builtin_amdgcn_s_setprio(1);
      #pragma unroll
      for (int dt = 0; dt < 4; ++dt){
        const int vrow = dt*16 + l15;
        bf16x8 vf0 = *(const bf16x8*)(vb + vrow*128 + ((l4*16) ^ sw));
        bf16x8 vf1 = *(const bf16x8*)(vb + vrow*128 + ((64 + l4*16) ^ sw));
        #pragma unroll
        for (int qi = 0; qi < 2; ++qi){
          oacc[qi][dt] = mfma16(pa[qi][0], vf0, oacc[qi][dt]);
          oacc[qi][dt] = mfma16(pa[qi][1], vf1, oacc[qi][dt]);
        }
      }
      __builtin_amdgcn_s_setprio(0);
    }

    if (pre){
      char* kd = (char*)Ks[cur^1];
      char* vd = (char*)Vs[cur^1];
      *(bf16x8*)(kd + srow*128 + scb)      = kl0;
      *(bf16x8*)(kd + (srow+32)*128 + scb) = kl1;
      *(bf16x8*)(vd + srow*128 + scb)      = vl0;
      *(bf16x8*)(vd + (srow+32)*128 + scb) = vl1;
    }
  }

  const int b = bh >> 4, h = bh & 15;
  #pragma unroll
  for (int qi = 0; qi < 2; ++qi){
    float inv = 1.0f / l_r[qi];
    float ir[4];
    #pragma unroll
    for (int r = 0; r < 4; ++r) ir[r] = __shfl(inv, l4*4 + r);
    #pragma unroll
    for (int r = 0; r < 4; ++r){
      int q = qw0 + qi*16 + l4*4 + r;
      unsigned short* orow = Ob + ((size_t)(b*SEQ + q))*D_MODEL + h*DKH;
      #pragma unroll
      for (int dt = 0; dt < 4; ++dt)
        orow[dt*16 + l15] = f2b(oacc[qi][dt][r] * ir[r]);
    }
  }
}

// ---------------- host orchestration ----------------
extern "C" void kernel_launch(void* const* d_in, const int* in_sizes, int n_in,
                              void* d_out, int out_size, void* d_ws, size_t ws_size,
                              hipStream_t stream)
{
  const float* x  = (const float*)d_in[0];
  const float* wq = (const float*)d_in[1];
  const float* wk = (const float*)d_in[2];
  const float* wv = (const float*)d_in[3];
  const float* wo = (const float*)d_in[4];
  const int* tp   = (const int*)d_in[5];
  float* out = (float*)d_out;

  unsigned short* ws = (unsigned short*)d_ws;
  size_t off = 0;
  unsigned short* xb   = ws + off; off += (size_t)MROWS*D_MODEL;
  unsigned short* wcat = ws + off; off += (size_t)3*D_MODEL*D_MODEL;
  unsigned short* wob  = ws + off; off += (size_t)D_MODEL*D_MODEL;
  unsigned short* qw   = ws + off; off += (size_t)BH_*SEQ*DKH;   // Q | K | V^T contiguous
  unsigned short* kw   = ws + off; off += (size_t)BH_*SEQ*DKH;
  unsigned short* vt   = ws + off; off += (size_t)BH_*SEQ*DKH;
  unsigned short* ao   = ws + off; off += (size_t)BH_*SEQ*DKH;
  float2* tab = (float2*)(ws + off); off += (size_t)SEQ*32*4;

  prep_kernel<<<12544, 256, 0, stream>>>(x, wq, wk, wv, wo, tp, xb, wcat, wob, tab);

  // fused QKV projection (+RoPE/scale on Q/K, +V transpose), N = 3072
  gemm_nt<0><<<dim3(3*D_MODEL/BN, MROWS/BM), 256, 0, stream>>>(xb, wcat, qw, tab,
                                                               MROWS, 3*D_MODEL, D_MODEL);

  attn_kernel<<<BH_*(SEQ/QB), 256, 0, stream>>>(qw, kw, vt, ao);

  gemm_nt<1><<<dim3(D_MODEL/BN, MROWS/BM), 256, 0, stream>>>(ao, wob, out, nullptr,
                                                             MROWS, D_MODEL, D_MODEL);
}